// Round 3
// baseline (545.274 us; speedup 1.0000x reference)
//
#include <hip/hip_runtime.h>
#include <hip/hip_bf16.h>

// Problem: B=256, A=128, F=512, D=6, C=512
// out[b,a,:] = (atoms[b,a,:] + sum_j atoms[b,bonds[b,a,j],:]) @ W[deg] + bias[deg]
// deg = count(bonds != -1), in 0..5.
//
// Inputs float32, output float32 (compared with bf16-scale tolerance).
// Strategy: bucket atoms by degree, then one gathered MFMA GEMM per degree
// with bf16 staging + fp32 accumulation.

#define NB 256
#define NA 128
#define NF 512
#define ND 6
#define NC 512
#define NATOMS (NB * NA)   // 32768

typedef __attribute__((ext_vector_type(8))) short frag8;
typedef __attribute__((ext_vector_type(4))) float f32x4;

static __device__ inline unsigned short f2bu(float f) {
    __hip_bfloat16 h = __float2bfloat16(f);
    return *reinterpret_cast<unsigned short*>(&h);
}
static __device__ inline unsigned int pack2(float a, float b) {
    return (unsigned int)f2bu(a) | ((unsigned int)f2bu(b) << 16);
}

// ---------------- kernel T: W[d][f][c] (f32) -> Wt[d][c][f] (bf16) ----------------
__global__ void transpose_w(const float* __restrict__ W,
                            __hip_bfloat16* __restrict__ Wt) {
    __shared__ float t[32][33];
    const int d  = blockIdx.z;
    const int c0 = blockIdx.x * 32;
    const int f0 = blockIdx.y * 32;
    #pragma unroll
    for (int r = 0; r < 32; r += 8)
        t[threadIdx.y + r][threadIdx.x] =
            W[((size_t)(d * NF + f0 + threadIdx.y + r)) * NC + c0 + threadIdx.x];
    __syncthreads();
    #pragma unroll
    for (int r = 0; r < 32; r += 8)
        Wt[((size_t)(d * NC + c0 + threadIdx.y + r)) * NF + f0 + threadIdx.x] =
            __float2bfloat16(t[threadIdx.x][threadIdx.y + r]);
}

// ---------------- kernel A: neighbor gather/sum (f32) -> summed (bf16) + bucketing --
// 1 wave per atom; lane handles floats [4*lane,4*lane+4) and [256+4*lane, ...+4).
__global__ __launch_bounds__(256) void sum_bucket(
    const float* __restrict__ atoms, const int* __restrict__ bonds,
    __hip_bfloat16* __restrict__ summed, int* __restrict__ counts,
    int* __restrict__ bucket) {
    const int tid  = threadIdx.x;
    const int wave = tid >> 6;
    const int lane = tid & 63;
    const int g    = blockIdx.x * 4 + wave;   // atom index [0, 32768)
    const float4* a4 = (const float4*)atoms;  // row = 128 float4

    float4 s0 = a4[(size_t)g * 128 + lane];
    float4 s1 = a4[(size_t)g * 128 + 64 + lane];

    const int rowbase = g & ~(NA - 1);  // (g / NA) * NA
    int deg = 0;
    #pragma unroll
    for (int j = 0; j < ND; ++j) {
        int n = bonds[g * ND + j];      // wave-uniform
        if (n >= 0) {
            ++deg;
            float4 v0 = a4[(size_t)(rowbase + n) * 128 + lane];
            float4 v1 = a4[(size_t)(rowbase + n) * 128 + 64 + lane];
            s0.x += v0.x; s0.y += v0.y; s0.z += v0.z; s0.w += v0.w;
            s1.x += v1.x; s1.y += v1.y; s1.z += v1.z; s1.w += v1.w;
        }
    }

    // summed row = 512 bf16 = 128 uint2; uint2 index u holds elements 4u..4u+3
    uint2 o0, o1;
    o0.x = pack2(s0.x, s0.y); o0.y = pack2(s0.z, s0.w);
    o1.x = pack2(s1.x, s1.y); o1.y = pack2(s1.z, s1.w);
    ((uint2*)summed)[(size_t)g * 128 + lane] = o0;
    ((uint2*)summed)[(size_t)g * 128 + 64 + lane] = o1;

    if (lane == 0) {
        int pos = atomicAdd(&counts[deg], 1);
        bucket[deg * NATOMS + pos] = g;
    }
}

// ---------------- kernel B: per-degree gathered GEMM ----------------
// grid: (256 row-tiles, 4 col-tiles, 6 degrees), block 256 (4 waves, 2x2).
// Tiles: BM=128, BN=128, BK=64. MFMA 16x16x32 bf16; each wave owns 64x64.
__global__ __launch_bounds__(256, 2) void gemm_deg(
    const __hip_bfloat16* __restrict__ summed, const __hip_bfloat16* __restrict__ Wt,
    const float* __restrict__ bias, const int* __restrict__ counts,
    const int* __restrict__ bucket, float* __restrict__ out) {
    const int d  = blockIdx.z;
    const int Md = counts[d];
    const int m0 = blockIdx.x * 128;
    if (m0 >= Md) return;
    const int n0 = blockIdx.y * 128;

    __shared__ __align__(16) __hip_bfloat16 sA[128 * 64];  // [row][k]
    __shared__ __align__(16) __hip_bfloat16 sB[128 * 64];  // [n][k]  (Wt rows)
    __shared__ int sRows[128];

    const int tid = threadIdx.x;
    if (tid < 128) {
        int r = m0 + tid;
        sRows[tid] = (r < Md) ? bucket[d * NATOMS + r] : -1;
    }
    __syncthreads();

    const int seg     = tid & 7;    // 16B segment within a 64-elem row
    const int baseRow = tid >> 3;   // 0..31
    int gr[4];
    #pragma unroll
    for (int r = 0; r < 4; ++r) {
        int q = sRows[baseRow + 32 * r];
        gr[r] = (q < 0) ? 0 : q;    // dummy row 0 for OOB (never stored)
    }

    const int lane = tid & 63;
    const int w    = tid >> 6;
    const int wy = w >> 1, wx = w & 1;
    const int quad = lane >> 4, l16 = lane & 15;

    f32x4 acc[4][4];
    #pragma unroll
    for (int i = 0; i < 4; ++i)
        #pragma unroll
        for (int j = 0; j < 4; ++j) acc[i][j] = (f32x4)0.0f;

    uint4* sA4 = (uint4*)sA;
    uint4* sB4 = (uint4*)sB;
    const uint4* sm4 = (const uint4*)summed;
    const uint4* wt4 = (const uint4*)Wt;

    for (int kt = 0; kt < NF / 64; ++kt) {
        const int k8 = kt * 8;  // k0 / 8 in uint4 units
        #pragma unroll
        for (int r = 0; r < 4; ++r) {
            const int row = baseRow + 32 * r;
            sA4[row * 8 + seg] = sm4[(size_t)gr[r] * 64 + k8 + seg];
            sB4[row * 8 + seg] = wt4[(size_t)(d * NC + n0 + row) * 64 + k8 + seg];
        }
        __syncthreads();
        #pragma unroll
        for (int ks = 0; ks < 64; ks += 32) {
            frag8 aF[4], bF[4];
            #pragma unroll
            for (int i = 0; i < 4; ++i)
                aF[i] = *(const frag8*)&sA[(wy * 64 + i * 16 + l16) * 64 + ks + quad * 8];
            #pragma unroll
            for (int j = 0; j < 4; ++j)
                bF[j] = *(const frag8*)&sB[(wx * 64 + j * 16 + l16) * 64 + ks + quad * 8];
            #pragma unroll
            for (int i = 0; i < 4; ++i)
                #pragma unroll
                for (int j = 0; j < 4; ++j)
                    acc[i][j] = __builtin_amdgcn_mfma_f32_16x16x32_bf16(
                        aF[i], bF[j], acc[i][j], 0, 0, 0);
        }
        __syncthreads();
    }

    // epilogue: C/D layout col = lane&15, row = quad*4 + reg; output is FLOAT32
    #pragma unroll
    for (int j = 0; j < 4; ++j) {
        const int n = n0 + wx * 64 + j * 16 + l16;
        const float bv = bias[d * NC + n];
        #pragma unroll
        for (int i = 0; i < 4; ++i) {
            #pragma unroll
            for (int r = 0; r < 4; ++r) {
                const int tr = wy * 64 + i * 16 + quad * 4 + r;
                const int g  = sRows[tr];
                if (g >= 0)
                    out[(size_t)g * NC + n] = acc[i][j][r] + bv;
            }
        }
    }
}

extern "C" void kernel_launch(void* const* d_in, const int* in_sizes, int n_in,
                              void* d_out, int out_size, void* d_ws, size_t ws_size,
                              hipStream_t stream) {
    const float* atoms = (const float*)d_in[0];
    const int*   bonds = (const int*)d_in[1];
    const float* W     = (const float*)d_in[2];
    const float* bias  = (const float*)d_in[3];
    float* out = (float*)d_out;

    // workspace layout
    char* ws = (char*)d_ws;
    int* counts = (int*)ws;                                   // 6 ints (zeroed)
    int* bucket = (int*)(ws + 1024);                          // 6*32768 ints = 786432 B
    __hip_bfloat16* Wt     = (__hip_bfloat16*)(ws + 1024 + 786432);            // 3 MB
    __hip_bfloat16* summed = (__hip_bfloat16*)(ws + 1024 + 786432 + 3145728);  // 32 MB

    hipMemsetAsync(counts, 0, 1024, stream);

    transpose_w<<<dim3(NC / 32, NF / 32, ND), dim3(32, 8), 0, stream>>>(W, Wt);

    sum_bucket<<<NATOMS / 4, 256, 0, stream>>>(atoms, bonds, summed, counts, bucket);

    gemm_deg<<<dim3(NATOMS / 128, NC / 128, ND), 256, 0, stream>>>(
        summed, Wt, bias, counts, bucket, out);
}

// Round 4
// 196.004 us; speedup vs baseline: 2.7820x; 2.7820x over previous
//
#include <hip/hip_runtime.h>
#include <hip/hip_bf16.h>

// Problem: B=256, A=128, F=512, D=6, C=512
// out[b,a,:] = (atoms[b,a,:] + sum_j atoms[b,bonds[b,a,j],:]) @ W[deg] + bias[deg]
// deg = count(bonds != -1), in 0..5.
//
// Inputs float32, output float32 (compared with bf16-scale tolerance).
// Strategy: bucket atoms by degree (LDS-aggregated, 192 global atomics total),
// atomic-free neighbor sum, then one gathered MFMA GEMM per degree
// (bf16 staging + fp32 accumulation).

#define NB 256
#define NA 128
#define NF 512
#define ND 6
#define NC 512
#define NATOMS (NB * NA)   // 32768

typedef __attribute__((ext_vector_type(8))) short frag8;
typedef __attribute__((ext_vector_type(4))) float f32x4;

static __device__ inline unsigned short f2bu(float f) {
    __hip_bfloat16 h = __float2bfloat16(f);
    return *reinterpret_cast<unsigned short*>(&h);
}
static __device__ inline unsigned int pack2(float a, float b) {
    return (unsigned int)f2bu(a) | ((unsigned int)f2bu(b) << 16);
}

// ---------------- kernel T: W[d][f][c] (f32) -> Wt[d][c][f] (bf16) ----------------
__global__ void transpose_w(const float* __restrict__ W,
                            __hip_bfloat16* __restrict__ Wt) {
    __shared__ float t[32][33];
    const int d  = blockIdx.z;
    const int c0 = blockIdx.x * 32;
    const int f0 = blockIdx.y * 32;
    #pragma unroll
    for (int r = 0; r < 32; r += 8)
        t[threadIdx.y + r][threadIdx.x] =
            W[((size_t)(d * NF + f0 + threadIdx.y + r)) * NC + c0 + threadIdx.x];
    __syncthreads();
    #pragma unroll
    for (int r = 0; r < 32; r += 8)
        Wt[((size_t)(d * NC + c0 + threadIdx.y + r)) * NF + f0 + threadIdx.x] =
            __float2bfloat16(t[threadIdx.x][threadIdx.y + r]);
}

// ---------------- kernel D: degree bucketing, LDS-aggregated ----------------
// 32 blocks x 256 threads x 4 atoms/thread. 6 global atomics per block (=192 total)
// instead of 1 per atom (=32768). Order within a degree bucket is arbitrary — GEMM
// only needs a partition.
__global__ __launch_bounds__(256) void bucket_atoms(
    const int* __restrict__ bonds, int* __restrict__ counts,
    int* __restrict__ bucket) {
    __shared__ int lcnt[ND];
    __shared__ int lbase[ND];
    const int tid = threadIdx.x;
    if (tid < ND) lcnt[tid] = 0;
    __syncthreads();
    int deg[4], loc[4], gg[4];
    #pragma unroll
    for (int i = 0; i < 4; ++i) {
        int g = blockIdx.x * 1024 + i * 256 + tid;
        gg[i] = g;
        int dg = 0;
        #pragma unroll
        for (int j = 0; j < ND; ++j) dg += (bonds[g * ND + j] >= 0);
        deg[i] = dg;
        loc[i] = atomicAdd(&lcnt[dg], 1);      // LDS atomic — cheap
    }
    __syncthreads();
    if (tid < ND) lbase[tid] = atomicAdd(&counts[tid], lcnt[tid]);  // 6 global/block
    __syncthreads();
    #pragma unroll
    for (int i = 0; i < 4; ++i)
        bucket[deg[i] * NATOMS + lbase[deg[i]] + loc[i]] = gg[i];
}

// ---------------- kernel A: neighbor gather/sum (f32) -> summed (bf16) ----------
// 1 wave per atom; atomic-free; all loads issued unconditionally (masked FMA),
// so the 6 neighbor gathers overlap in one memory round-trip.
__global__ __launch_bounds__(256) void sum_neigh(
    const float* __restrict__ atoms, const int* __restrict__ bonds,
    __hip_bfloat16* __restrict__ summed) {
    const int tid  = threadIdx.x;
    const int wave = tid >> 6;
    const int lane = tid & 63;
    const int g    = blockIdx.x * 4 + wave;   // atom index [0, 32768)
    const float4* a4 = (const float4*)atoms;  // row = 128 float4

    int   nb[ND];
    float msk[ND];
    #pragma unroll
    for (int j = 0; j < ND; ++j) {
        int n = bonds[g * ND + j];
        msk[j] = (n >= 0) ? 1.0f : 0.0f;
        nb[j]  = (n >= 0) ? n : 0;            // dummy row 0, masked out
    }
    const int rowbase = g & ~(NA - 1);        // (g / NA) * NA

    float4 s0 = a4[(size_t)g * 128 + lane];
    float4 s1 = a4[(size_t)g * 128 + 64 + lane];
    float4 v0[ND], v1[ND];
    #pragma unroll
    for (int j = 0; j < ND; ++j) {
        const size_t base = (size_t)(rowbase + nb[j]) * 128;
        v0[j] = a4[base + lane];
        v1[j] = a4[base + 64 + lane];
    }
    #pragma unroll
    for (int j = 0; j < ND; ++j) {
        s0.x = fmaf(v0[j].x, msk[j], s0.x); s0.y = fmaf(v0[j].y, msk[j], s0.y);
        s0.z = fmaf(v0[j].z, msk[j], s0.z); s0.w = fmaf(v0[j].w, msk[j], s0.w);
        s1.x = fmaf(v1[j].x, msk[j], s1.x); s1.y = fmaf(v1[j].y, msk[j], s1.y);
        s1.z = fmaf(v1[j].z, msk[j], s1.z); s1.w = fmaf(v1[j].w, msk[j], s1.w);
    }

    // summed row = 512 bf16 = 128 uint2; uint2 index u holds elements 4u..4u+3
    uint2 o0, o1;
    o0.x = pack2(s0.x, s0.y); o0.y = pack2(s0.z, s0.w);
    o1.x = pack2(s1.x, s1.y); o1.y = pack2(s1.z, s1.w);
    ((uint2*)summed)[(size_t)g * 128 + lane] = o0;
    ((uint2*)summed)[(size_t)g * 128 + 64 + lane] = o1;
}

// ---------------- kernel B: per-degree gathered GEMM ----------------
// grid: (256 row-tiles, 4 col-tiles, 6 degrees), block 256 (4 waves, 2x2).
// Tiles: BM=128, BN=128, BK=64. MFMA 16x16x32 bf16; each wave owns 64x64.
__global__ __launch_bounds__(256, 2) void gemm_deg(
    const __hip_bfloat16* __restrict__ summed, const __hip_bfloat16* __restrict__ Wt,
    const float* __restrict__ bias, const int* __restrict__ counts,
    const int* __restrict__ bucket, float* __restrict__ out) {
    const int d  = blockIdx.z;
    const int Md = counts[d];
    const int m0 = blockIdx.x * 128;
    if (m0 >= Md) return;
    const int n0 = blockIdx.y * 128;

    __shared__ __align__(16) __hip_bfloat16 sA[128 * 64];  // [row][k]
    __shared__ __align__(16) __hip_bfloat16 sB[128 * 64];  // [n][k]  (Wt rows)
    __shared__ int sRows[128];

    const int tid = threadIdx.x;
    if (tid < 128) {
        int r = m0 + tid;
        sRows[tid] = (r < Md) ? bucket[d * NATOMS + r] : -1;
    }
    __syncthreads();

    const int seg     = tid & 7;    // 16B segment within a 64-elem row
    const int baseRow = tid >> 3;   // 0..31
    int gr[4];
    #pragma unroll
    for (int r = 0; r < 4; ++r) {
        int q = sRows[baseRow + 32 * r];
        gr[r] = (q < 0) ? 0 : q;    // dummy row 0 for OOB (never stored)
    }

    const int lane = tid & 63;
    const int w    = tid >> 6;
    const int wy = w >> 1, wx = w & 1;
    const int quad = lane >> 4, l16 = lane & 15;

    f32x4 acc[4][4];
    #pragma unroll
    for (int i = 0; i < 4; ++i)
        #pragma unroll
        for (int j = 0; j < 4; ++j) acc[i][j] = (f32x4)0.0f;

    uint4* sA4 = (uint4*)sA;
    uint4* sB4 = (uint4*)sB;
    const uint4* sm4 = (const uint4*)summed;
    const uint4* wt4 = (const uint4*)Wt;

    for (int kt = 0; kt < NF / 64; ++kt) {
        const int k8 = kt * 8;  // k0 / 8 in uint4 units
        #pragma unroll
        for (int r = 0; r < 4; ++r) {
            const int row = baseRow + 32 * r;
            sA4[row * 8 + seg] = sm4[(size_t)gr[r] * 64 + k8 + seg];
            sB4[row * 8 + seg] = wt4[(size_t)(d * NC + n0 + row) * 64 + k8 + seg];
        }
        __syncthreads();
        #pragma unroll
        for (int ks = 0; ks < 64; ks += 32) {
            frag8 aF[4], bF[4];
            #pragma unroll
            for (int i = 0; i < 4; ++i)
                aF[i] = *(const frag8*)&sA[(wy * 64 + i * 16 + l16) * 64 + ks + quad * 8];
            #pragma unroll
            for (int j = 0; j < 4; ++j)
                bF[j] = *(const frag8*)&sB[(wx * 64 + j * 16 + l16) * 64 + ks + quad * 8];
            #pragma unroll
            for (int i = 0; i < 4; ++i)
                #pragma unroll
                for (int j = 0; j < 4; ++j)
                    acc[i][j] = __builtin_amdgcn_mfma_f32_16x16x32_bf16(
                        aF[i], bF[j], acc[i][j], 0, 0, 0);
        }
        __syncthreads();
    }

    // epilogue: C/D layout col = lane&15, row = quad*4 + reg; output is FLOAT32
    #pragma unroll
    for (int j = 0; j < 4; ++j) {
        const int n = n0 + wx * 64 + j * 16 + l16;
        const float bv = bias[d * NC + n];
        #pragma unroll
        for (int i = 0; i < 4; ++i) {
            #pragma unroll
            for (int r = 0; r < 4; ++r) {
                const int tr = wy * 64 + i * 16 + quad * 4 + r;
                const int g  = sRows[tr];
                if (g >= 0)
                    out[(size_t)g * NC + n] = acc[i][j][r] + bv;
            }
        }
    }
}

extern "C" void kernel_launch(void* const* d_in, const int* in_sizes, int n_in,
                              void* d_out, int out_size, void* d_ws, size_t ws_size,
                              hipStream_t stream) {
    const float* atoms = (const float*)d_in[0];
    const int*   bonds = (const int*)d_in[1];
    const float* W     = (const float*)d_in[2];
    const float* bias  = (const float*)d_in[3];
    float* out = (float*)d_out;

    // workspace layout
    char* ws = (char*)d_ws;
    int* counts = (int*)ws;                                   // 6 ints (zeroed)
    int* bucket = (int*)(ws + 1024);                          // 6*32768 ints = 786432 B
    __hip_bfloat16* Wt     = (__hip_bfloat16*)(ws + 1024 + 786432);            // 3 MB
    __hip_bfloat16* summed = (__hip_bfloat16*)(ws + 1024 + 786432 + 3145728);  // 32 MB

    hipMemsetAsync(counts, 0, 1024, stream);

    transpose_w<<<dim3(NC / 32, NF / 32, ND), dim3(32, 8), 0, stream>>>(W, Wt);

    bucket_atoms<<<NATOMS / 1024, 256, 0, stream>>>(bonds, counts, bucket);

    sum_neigh<<<NATOMS / 4, 256, 0, stream>>>(atoms, bonds, summed);

    gemm_deg<<<dim3(NATOMS / 128, NC / 128, ND), 256, 0, stream>>>(
        summed, Wt, bias, counts, bucket, out);
}

// Round 5
// 184.247 us; speedup vs baseline: 2.9595x; 1.0638x over previous
//
#include <hip/hip_runtime.h>
#include <hip/hip_bf16.h>

// Problem: B=256, A=128, F=512, D=6, C=512
// out[b,a,:] = (atoms[b,a,:] + sum_j atoms[b,bonds[b,a,j],:]) @ W[deg] + bias[deg]
// deg = count(bonds != -1), in 0..5.
//
// Inputs float32, output float32 (compared with bf16-scale tolerance).
// R4: gemm grid reordered (row-tile slow) to kill CU aliasing; staging via
// global_load_lds width=16 (DMA straight to LDS, gather on the global side).

#define NB 256
#define NA 128
#define NF 512
#define ND 6
#define NC 512
#define NATOMS (NB * NA)   // 32768

typedef __attribute__((ext_vector_type(8))) short frag8;
typedef __attribute__((ext_vector_type(4))) float f32x4;

static __device__ inline unsigned short f2bu(float f) {
    __hip_bfloat16 h = __float2bfloat16(f);
    return *reinterpret_cast<unsigned short*>(&h);
}
static __device__ inline unsigned int pack2(float a, float b) {
    return (unsigned int)f2bu(a) | ((unsigned int)f2bu(b) << 16);
}
static __device__ inline void async16(const void* g, void* l) {
    __builtin_amdgcn_global_load_lds(
        (const __attribute__((address_space(1))) void*)g,
        (__attribute__((address_space(3))) void*)l, 16, 0, 0);
}

// ---------------- kernel T: W[d][f][c] (f32) -> Wt[d][c][f] (bf16) ----------------
__global__ void transpose_w(const float* __restrict__ W,
                            __hip_bfloat16* __restrict__ Wt) {
    __shared__ float t[32][33];
    const int d  = blockIdx.z;
    const int c0 = blockIdx.x * 32;
    const int f0 = blockIdx.y * 32;
    #pragma unroll
    for (int r = 0; r < 32; r += 8)
        t[threadIdx.y + r][threadIdx.x] =
            W[((size_t)(d * NF + f0 + threadIdx.y + r)) * NC + c0 + threadIdx.x];
    __syncthreads();
    #pragma unroll
    for (int r = 0; r < 32; r += 8)
        Wt[((size_t)(d * NC + c0 + threadIdx.y + r)) * NF + f0 + threadIdx.x] =
            __float2bfloat16(t[threadIdx.x][threadIdx.y + r]);
}

// ---------------- kernel D: degree bucketing, LDS-aggregated ----------------
__global__ __launch_bounds__(256) void bucket_atoms(
    const int* __restrict__ bonds, int* __restrict__ counts,
    int* __restrict__ bucket) {
    __shared__ int lcnt[ND];
    __shared__ int lbase[ND];
    const int tid = threadIdx.x;
    if (tid < ND) lcnt[tid] = 0;
    __syncthreads();
    int deg[4], loc[4], gg[4];
    #pragma unroll
    for (int i = 0; i < 4; ++i) {
        int g = blockIdx.x * 1024 + i * 256 + tid;
        gg[i] = g;
        int dg = 0;
        #pragma unroll
        for (int j = 0; j < ND; ++j) dg += (bonds[g * ND + j] >= 0);
        deg[i] = dg;
        loc[i] = atomicAdd(&lcnt[dg], 1);      // LDS atomic — cheap
    }
    __syncthreads();
    if (tid < ND) lbase[tid] = atomicAdd(&counts[tid], lcnt[tid]);  // 6 global/block
    __syncthreads();
    #pragma unroll
    for (int i = 0; i < 4; ++i)
        bucket[deg[i] * NATOMS + lbase[deg[i]] + loc[i]] = gg[i];
}

// ---------------- kernel A: neighbor gather/sum (f32) -> summed (bf16) ----------
__global__ __launch_bounds__(256) void sum_neigh(
    const float* __restrict__ atoms, const int* __restrict__ bonds,
    __hip_bfloat16* __restrict__ summed) {
    const int tid  = threadIdx.x;
    const int wave = tid >> 6;
    const int lane = tid & 63;
    const int g    = blockIdx.x * 4 + wave;   // atom index [0, 32768)
    const float4* a4 = (const float4*)atoms;  // row = 128 float4

    int   nb[ND];
    float msk[ND];
    #pragma unroll
    for (int j = 0; j < ND; ++j) {
        int n = bonds[g * ND + j];
        msk[j] = (n >= 0) ? 1.0f : 0.0f;
        nb[j]  = (n >= 0) ? n : 0;            // dummy row 0, masked out
    }
    const int rowbase = g & ~(NA - 1);        // (g / NA) * NA

    float4 s0 = a4[(size_t)g * 128 + lane];
    float4 s1 = a4[(size_t)g * 128 + 64 + lane];
    float4 v0[ND], v1[ND];
    #pragma unroll
    for (int j = 0; j < ND; ++j) {
        const size_t base = (size_t)(rowbase + nb[j]) * 128;
        v0[j] = a4[base + lane];
        v1[j] = a4[base + 64 + lane];
    }
    #pragma unroll
    for (int j = 0; j < ND; ++j) {
        s0.x = fmaf(v0[j].x, msk[j], s0.x); s0.y = fmaf(v0[j].y, msk[j], s0.y);
        s0.z = fmaf(v0[j].z, msk[j], s0.z); s0.w = fmaf(v0[j].w, msk[j], s0.w);
        s1.x = fmaf(v1[j].x, msk[j], s1.x); s1.y = fmaf(v1[j].y, msk[j], s1.y);
        s1.z = fmaf(v1[j].z, msk[j], s1.z); s1.w = fmaf(v1[j].w, msk[j], s1.w);
    }

    uint2 o0, o1;
    o0.x = pack2(s0.x, s0.y); o0.y = pack2(s0.z, s0.w);
    o1.x = pack2(s1.x, s1.y); o1.y = pack2(s1.z, s1.w);
    ((uint2*)summed)[(size_t)g * 128 + lane] = o0;
    ((uint2*)summed)[(size_t)g * 128 + 64 + lane] = o1;
}

// ---------------- kernel B: per-degree gathered GEMM ----------------
// grid: (24 = col*deg fast, 256 row-tiles slow) — working blocks are the first
// ~1032 dispatched, spread over all 256 CUs. Block 256 threads (4 waves, 2x2).
// Tiles: BM=128, BN=128, BK=64. MFMA 16x16x32 bf16; each wave owns 64x64.
// Staging: global_load_lds width=16; LDS dest = wave-uniform base + lane*16,
// global addr per-lane (A rows gathered via bucket).
__global__ __launch_bounds__(256, 4) void gemm_deg(
    const __hip_bfloat16* __restrict__ summed, const __hip_bfloat16* __restrict__ Wt,
    const float* __restrict__ bias, const int* __restrict__ counts,
    const int* __restrict__ bucket, float* __restrict__ out) {
    const int bx = blockIdx.x;          // 0..23
    const int d  = bx % ND;
    const int n0 = (bx / ND) * 128;
    const int Md = counts[d];
    const int m0 = blockIdx.y * 128;
    if (m0 >= Md) return;

    __shared__ __align__(16) __hip_bfloat16 sA[128 * 64];  // [row][k]
    __shared__ __align__(16) __hip_bfloat16 sB[128 * 64];  // [n][k]  (Wt rows)
    __shared__ int sRows[128];

    const int tid = threadIdx.x;
    if (tid < 128) {
        int r = m0 + tid;
        sRows[tid] = (r < Md) ? bucket[d * NATOMS + r] : -1;
    }
    __syncthreads();

    const int lane = tid & 63;
    const int w    = tid >> 6;
    const int srow = lane >> 3;     // 0..7 within an 8-row chunk
    const int seg  = lane & 7;      // 16B segment within a 64-elem row

    // per-wave staging: wave w stages rows w*32 + c*8 + srow, c = 0..3
    const char* smB = (const char*)summed;
    const char* wtB = (const char*)Wt + (size_t)(d * NC + n0) * (NF * 2);
    size_t gA[4];
    int    rowc[4];
    #pragma unroll
    for (int c = 0; c < 4; ++c) {
        rowc[c] = w * 32 + c * 8 + srow;
        int q = sRows[rowc[c]];
        gA[c] = (size_t)((q < 0) ? 0 : q) * (NF * 2);   // dummy row 0 (never stored)
    }

    const int quad = lane >> 4, l16 = lane & 15;
    const int wy = w >> 1, wx = w & 1;

    f32x4 acc[4][4];
    #pragma unroll
    for (int i = 0; i < 4; ++i)
        #pragma unroll
        for (int j = 0; j < 4; ++j) acc[i][j] = (f32x4)0.0f;

    for (int kt = 0; kt < NF / 64; ++kt) {
        const int koff = kt * 128 + seg * 16;   // byte offset within a 1024B row
        #pragma unroll
        for (int c = 0; c < 4; ++c) {
            async16(smB + gA[c] + koff, &sA[(w * 32 + c * 8) * 64]);
            async16(wtB + (size_t)rowc[c] * (NF * 2) + koff, &sB[(w * 32 + c * 8) * 64]);
        }
        __syncthreads();
        #pragma unroll
        for (int ks = 0; ks < 64; ks += 32) {
            frag8 aF[4], bF[4];
            #pragma unroll
            for (int i = 0; i < 4; ++i)
                aF[i] = *(const frag8*)&sA[(wy * 64 + i * 16 + l16) * 64 + ks + quad * 8];
            #pragma unroll
            for (int j = 0; j < 4; ++j)
                bF[j] = *(const frag8*)&sB[(wx * 64 + j * 16 + l16) * 64 + ks + quad * 8];
            #pragma unroll
            for (int i = 0; i < 4; ++i)
                #pragma unroll
                for (int j = 0; j < 4; ++j)
                    acc[i][j] = __builtin_amdgcn_mfma_f32_16x16x32_bf16(
                        aF[i], bF[j], acc[i][j], 0, 0, 0);
        }
        __syncthreads();
    }

    // epilogue: C/D layout col = lane&15, row = quad*4 + reg; output is FLOAT32
    #pragma unroll
    for (int j = 0; j < 4; ++j) {
        const int n = n0 + wx * 64 + j * 16 + l16;
        const float bv = bias[d * NC + n];
        #pragma unroll
        for (int i = 0; i < 4; ++i) {
            #pragma unroll
            for (int r = 0; r < 4; ++r) {
                const int tr = wy * 64 + i * 16 + quad * 4 + r;
                const int g  = sRows[tr];
                if (g >= 0)
                    out[(size_t)g * NC + n] = acc[i][j][r] + bv;
            }
        }
    }
}

extern "C" void kernel_launch(void* const* d_in, const int* in_sizes, int n_in,
                              void* d_out, int out_size, void* d_ws, size_t ws_size,
                              hipStream_t stream) {
    const float* atoms = (const float*)d_in[0];
    const int*   bonds = (const int*)d_in[1];
    const float* W     = (const float*)d_in[2];
    const float* bias  = (const float*)d_in[3];
    float* out = (float*)d_out;

    // workspace layout
    char* ws = (char*)d_ws;
    int* counts = (int*)ws;                                   // 6 ints (zeroed)
    int* bucket = (int*)(ws + 1024);                          // 6*32768 ints = 786432 B
    __hip_bfloat16* Wt     = (__hip_bfloat16*)(ws + 1024 + 786432);            // 3 MB
    __hip_bfloat16* summed = (__hip_bfloat16*)(ws + 1024 + 786432 + 3145728);  // 32 MB

    hipMemsetAsync(counts, 0, 1024, stream);

    transpose_w<<<dim3(NC / 32, NF / 32, ND), dim3(32, 8), 0, stream>>>(W, Wt);

    bucket_atoms<<<NATOMS / 1024, 256, 0, stream>>>(bonds, counts, bucket);

    sum_neigh<<<NATOMS / 4, 256, 0, stream>>>(atoms, bonds, summed);

    gemm_deg<<<dim3(24, NATOMS / 128), 256, 0, stream>>>(
        summed, Wt, bias, counts, bucket, out);
}